// Round 4
// baseline (243.804 us; speedup 1.0000x reference)
//
#include <hip/hip_runtime.h>
#include <hip/hip_cooperative_groups.h>
#include <stdint.h>
namespace cg = cooperative_groups;

#define BB 64
#define LL 16384
#define PP 256
#define NCH 8          // chunks per row
#define CHK 2048       // tokens per chunk
#define NT 256         // threads per block
#define TPT 8          // tokens per thread
#define SEGW 512       // segbits words per row (16384 bits)
#define WW (LL / 32)   // words per row for fallback path

__device__ __forceinline__ int ald(const int* p) {
    return __hip_atomic_load(p, __ATOMIC_RELAXED, __HIP_MEMORY_SCOPE_AGENT);
}
__device__ __forceinline__ void ast(int* p, int v) {
    __hip_atomic_store(p, v, __ATOMIC_RELAXED, __HIP_MEMORY_SCOPE_AGENT);
}
__device__ __forceinline__ unsigned aldu(const unsigned* p) {
    return __hip_atomic_load(p, __ATOMIC_RELAXED, __HIP_MEMORY_SCOPE_AGENT);
}
__device__ __forceinline__ void astu(unsigned* p, unsigned v) {
    __hip_atomic_store(p, v, __ATOMIC_RELAXED, __HIP_MEMORY_SCOPE_AGENT);
}

// exclusive scan over NT=256 threads (4 waves); *s_tot = block total
__device__ __forceinline__ int exscan256(int v, int tid, int* s_w, int* s_tot) {
    __syncthreads();    // protect s_w/s_tot reuse across calls
    const int lane = tid & 63, wv = tid >> 6;
    int inc = v;
#pragma unroll
    for (int off = 1; off < 64; off <<= 1) {
        int n = __shfl_up(inc, off, 64);
        if (lane >= off) inc += n;
    }
    if (lane == 63) s_w[wv] = inc;
    __syncthreads();
    if (tid == 0) {
        int t = 0;
#pragma unroll
        for (int w = 0; w < 4; ++w) { int u = s_w[w]; s_w[w] = t; t += u; }
        *s_tot = t;
    }
    __syncthreads();
    return inc - v + s_w[wv];
}

// ================= single cooperative kernel =================
__global__ void __launch_bounds__(NT) coop_seg(
    const int* __restrict__ g_ids, const int* __restrict__ g_amask,
    const int* __restrict__ g_t2p, const int* __restrict__ g_kp,
    const int* __restrict__ g_qp, int* __restrict__ g_out,
    unsigned* __restrict__ g_segbits, int* __restrict__ aggr_bnd,
    int* __restrict__ aggr_kept, int* __restrict__ aggr_lastv)
{
    __shared__ unsigned char kp[PP];
    __shared__ unsigned s_segw[66];
    __shared__ int s_w[4];
    __shared__ int s_tot;
    __shared__ int s_lastv;
    __shared__ int s_k[NCH];
    __shared__ int s_l[NCH];

    cg::grid_group gg = cg::this_grid();
    const int chunk = blockIdx.x;          // 0..7
    const int row   = blockIdx.y;          // 0..63
    const int tid   = threadIdx.x;         // 0..255
    const int bl    = row * NCH + chunk;
    const int pos0  = chunk * CHK + tid * TPT;
    const int rowoff = row * LL;

    // ---------------- Phase 1: masks + local boundary scan ----------------
    kp[tid] = (g_kp[row * PP + tid] != 0);
    // zero segment bitset (agent-scope stores so remote RMWs see them)
    if (tid < 64) astu(&g_segbits[bl * 64 + tid], 0u);
    int qp = g_qp[row];
    qp = qp < 0 ? 0 : (qp > LL - 1 ? LL - 1 : qp);
    __syncthreads();

    const int4* idp = (const int4*)(g_ids + rowoff + pos0);
    const int4* amp = (const int4*)(g_amask + rowoff + pos0);
    const int4* tpp = (const int4*)(g_t2p + rowoff + pos0);
    int4 i0 = idp[0], i1 = idp[1];
    unsigned v8 = 0, b8 = 0, m8 = 0;
    {
        int4 a0 = amp[0], a1 = amp[1], p0 = tpp[0], p1 = tpp[1];
        int idsv[8] = {i0.x, i0.y, i0.z, i0.w, i1.x, i1.y, i1.z, i1.w};
        int amv[8]  = {a0.x, a0.y, a0.z, a0.w, a1.x, a1.y, a1.z, a1.w};
        int tpv[8]  = {p0.x, p0.y, p0.z, p0.w, p1.x, p1.y, p1.z, p1.w};
#pragma unroll
        for (int j = 0; j < TPT; ++j) {
            const int va = (amv[j] != 0);
            const int bd = va && (idsv[j] == 13 || idsv[j] == 30);
            int pg = tpv[j];
            pg = pg < 0 ? 0 : (pg > PP - 1 ? PP - 1 : pg);
            const int m1 = va && (kp[pg] || (pos0 + j) >= qp);
            v8 |= (unsigned)va << j;
            b8 |= (unsigned)bd << j;
            m8 |= (unsigned)m1 << j;
        }
    }
    const int sb_local = exscan256(__popc(b8), tid, s_w, &s_tot);
    const int bnd_blk = s_tot;
    if (tid == 0) ast(&aggr_bnd[bl], bnd_blk);
    gg.sync();

    // ---------------- Phase 2: global seg bases + rescue accumulate ----------------
    int chunk_off = 0;
    for (int c = 0; c < chunk; ++c) chunk_off += ald(&aggr_bnd[row * NCH + c]);
    const int segb = chunk_off + sb_local;       // this thread's first-token segment id base
    const int w0 = chunk_off >> 5;
    const int nw = ((chunk_off + bnd_blk) >> 5) - w0 + 1;   // seg words this chunk touches (<=65)

    const int rel = qp - pos0;
    const unsigned ctx = rel <= 0 ? 0u : (rel >= TPT ? 0xFFu : ((1u << rel) - 1u));

    for (int i = tid; i < 66; i += NT) s_segw[i] = 0u;
    __syncthreads();
    {
        unsigned cands = m8 & ctx;   // in-ctx kept tokens light their segment
        while (cands) {
            const int j = __ffs(cands) - 1;
            cands &= cands - 1;
            const int s = segb + __popc(b8 & ((1u << j) - 1u));
            atomicOr(&s_segw[(s >> 5) - w0], 1u << (s & 31));
        }
    }
    __syncthreads();
    if (tid < nw) {
        const unsigned w = s_segw[tid];
        if (w) atomicOr(&g_segbits[row * SEGW + w0 + tid], w);  // device-scope
    }
    gg.sync();

    // ---------------- Phase 3: rescue read + local compaction scan ----------------
    if (tid < nw) s_segw[tid] = aldu(&g_segbits[row * SEGW + w0 + tid]);
    if (tid == 0) s_lastv = -1;
    __syncthreads();
    unsigned m2 = m8;
    {
        unsigned cand = v8 & ctx & ~m8;
        while (cand) {
            const int j = __ffs(cand) - 1;
            cand &= cand - 1;
            const int s = segb + __popc(b8 & ((1u << j) - 1u));
            if ((s_segw[(s >> 5) - w0] >> (s & 31)) & 1u) m2 |= 1u << j;
        }
    }
    {
        const int locallast = v8 ? pos0 + (31 - __clz(v8)) : -1;
        atomicMax(&s_lastv, locallast);
    }
    const int cb_local = exscan256(__popc(m2), tid, s_w, &s_tot);
    if (tid == 0) {
        ast(&aggr_kept[bl], s_tot);
        ast(&aggr_lastv[bl], s_lastv);
    }
    gg.sync();

    // ---------------- Phase 4: row prefix, fallback, scatter, outputs ----------------
    if (tid < NCH) {
        s_k[tid] = ald(&aggr_kept[row * NCH + tid]);
        s_l[tid] = ald(&aggr_lastv[row * NCH + tid]);
    }
    __syncthreads();
    int lk = 0, prefix = 0;
#pragma unroll
    for (int c = 0; c < NCH; ++c) {
        const int k = s_k[c];
        lk += k;
        if (c < chunk) prefix += k;
    }
    int cbase = prefix + cb_local;

    if (lk == 0) {   // fallback: keep last valid token (or position 0)
        int fb = -1;
#pragma unroll
        for (int c = 0; c < NCH; ++c) fb = fb > s_l[c] ? fb : s_l[c];
        if (fb < 0) fb = 0;
        if (chunk == (fb >> 11) && tid == ((fb & (CHK - 1)) >> 3)) {
            int idsv[8] = {i0.x, i0.y, i0.z, i0.w, i1.x, i1.y, i1.z, i1.w};
            g_out[rowoff] = idsv[fb & 7];
        }
        lk = 1;
        m2 = 0u;
    }

    // scatter kept ids (stable, monotone destinations)
    if (m2 == 0xFFu && (cbase & 3) == 0) {
        ((int4*)(g_out + rowoff + cbase))[0] = i0;
        ((int4*)(g_out + rowoff + cbase))[1] = i1;
    } else if (m2) {
        int idsv[8] = {i0.x, i0.y, i0.z, i0.w, i1.x, i1.y, i1.z, i1.w};
        int cc = rowoff + cbase;
        unsigned mm = m2;
        while (mm) {
            const int j = __ffs(mm) - 1;
            mm &= mm - 1;
            g_out[cc++] = idsv[j];
        }
    }

    // pad ids tail
    const int g = rowoff + pos0;
    if (pos0 >= lk) {
        int4 z; z.x = z.y = z.z = z.w = 0;
        ((int4*)(g_out + g))[0] = z;
        ((int4*)(g_out + g))[1] = z;
    } else if (pos0 + TPT > lk) {
#pragma unroll
        for (int j = 0; j < TPT; ++j)
            if (pos0 + j >= lk) g_out[g + j] = 0;
    }

    // attn / pos
    int* attn = g_out + (size_t)BB * LL;
    int* pos  = g_out + (size_t)2 * BB * LL;
    int4 a0, a1, q0, q1;
    a0.x = (pos0 + 0) < lk; a0.y = (pos0 + 1) < lk; a0.z = (pos0 + 2) < lk; a0.w = (pos0 + 3) < lk;
    a1.x = (pos0 + 4) < lk; a1.y = (pos0 + 5) < lk; a1.z = (pos0 + 6) < lk; a1.w = (pos0 + 7) < lk;
    q0.x = a0.x ? pos0 + 0 : 0; q0.y = a0.y ? pos0 + 1 : 0; q0.z = a0.z ? pos0 + 2 : 0; q0.w = a0.w ? pos0 + 3 : 0;
    q1.x = a1.x ? pos0 + 4 : 0; q1.y = a1.y ? pos0 + 5 : 0; q1.z = a1.z ? pos0 + 6 : 0; q1.w = a1.w ? pos0 + 7 : 0;
    ((int4*)(attn + g))[0] = a0;
    ((int4*)(attn + g))[1] = a1;
    ((int4*)(pos + g))[0] = q0;
    ((int4*)(pos + g))[1] = q1;
}

// ================= fallback path: proven 3-kernel pipeline =================
__global__ void __launch_bounds__(256) k1_masks(
    const int* __restrict__ g_ids, const int* __restrict__ g_amask,
    const int* __restrict__ g_t2p, const int* __restrict__ g_kp,
    const int* __restrict__ g_qp,
    unsigned* __restrict__ validw, unsigned* __restrict__ bndw,
    unsigned* __restrict__ mask1w)
{
    __shared__ unsigned char kp[PP];
    const int chunk = blockIdx.x, row = blockIdx.y, t = threadIdx.x;
    if (t < PP) kp[t] = (g_kp[row * PP + t] != 0);
    int qp = g_qp[row];
    qp = qp < 0 ? 0 : (qp > LL - 1 ? LL - 1 : qp);
    __syncthreads();
    const int pos0 = chunk * 2048 + t * 8;
    const int g = row * LL + pos0;
    const int4* idp = (const int4*)(g_ids + g);
    const int4* amp = (const int4*)(g_amask + g);
    const int4* tpp = (const int4*)(g_t2p + g);
    unsigned v8 = 0, b8 = 0, m8 = 0;
#pragma unroll
    for (int jv = 0; jv < 2; ++jv) {
        int4 iv = idp[jv], av = amp[jv], pv = tpp[jv];
        int idsv[4] = {iv.x, iv.y, iv.z, iv.w};
        int amv[4]  = {av.x, av.y, av.z, av.w};
        int tpv[4]  = {pv.x, pv.y, pv.z, pv.w};
#pragma unroll
        for (int k = 0; k < 4; ++k) {
            const int j = jv * 4 + k;
            const int va = (amv[k] != 0);
            const int bd = va && (idsv[k] == 13 || idsv[k] == 30);
            int pg = tpv[k];
            pg = pg < 0 ? 0 : (pg > PP - 1 ? PP - 1 : pg);
            const int m1 = va && (kp[pg] || (pos0 + j) >= qp);
            v8 |= (unsigned)va << j; b8 |= (unsigned)bd << j; m8 |= (unsigned)m1 << j;
        }
    }
    const int sub = t & 3, sh = 8 * sub;
    unsigned vw = v8 << sh, bw = b8 << sh, mw = m8 << sh;
    vw |= __shfl_xor(vw, 1, 64); vw |= __shfl_xor(vw, 2, 64);
    bw |= __shfl_xor(bw, 1, 64); bw |= __shfl_xor(bw, 2, 64);
    mw |= __shfl_xor(mw, 1, 64); mw |= __shfl_xor(mw, 2, 64);
    if (sub == 0) {
        const int widx = row * WW + chunk * 64 + (t >> 2);
        validw[widx] = vw; bndw[widx] = bw; mask1w[widx] = mw;
    }
}

__device__ __forceinline__ int exscan512(int v, int tid, int* s_wave, int* s_total) {
    __syncthreads();
    const int lane = tid & 63, wv = tid >> 6;
    int inc = v;
#pragma unroll
    for (int off = 1; off < 64; off <<= 1) {
        int n = __shfl_up(inc, off, 64);
        if (lane >= off) inc += n;
    }
    if (lane == 63) s_wave[wv] = inc;
    __syncthreads();
    if (wv == 0) {
        int wval = (lane < 8) ? s_wave[lane] : 0;
        int winc = wval;
#pragma unroll
        for (int off = 1; off < 8; off <<= 1) {
            int n = __shfl_up(winc, off, 64);
            if (lane >= off) winc += n;
        }
        if (lane < 8) s_wave[lane] = winc - wval;
        if (lane == 7) *s_total = winc;
    }
    __syncthreads();
    return inc - v + s_wave[wv];
}

__global__ void __launch_bounds__(512) k2_scan(
    const unsigned* __restrict__ validw, const unsigned* __restrict__ bndw,
    const unsigned* __restrict__ mask1w, const int* __restrict__ g_qp,
    unsigned* __restrict__ mask2w, int* __restrict__ wordscan,
    int* __restrict__ lkarr)
{
    __shared__ unsigned segbits[WW];
    __shared__ int s_wave[8];
    __shared__ int s_total;
    __shared__ int s_fb;
    const int row = blockIdx.x, t = threadIdx.x;
    segbits[t] = 0u;
    int qp = g_qp[row];
    qp = qp < 0 ? 0 : (qp > LL - 1 ? LL - 1 : qp);
    const unsigned vwd = validw[row * WW + t];
    const unsigned bwd = bndw[row * WW + t];
    const unsigned mwd = mask1w[row * WW + t];
    const int segbase = exscan512(__popc(bwd), t, s_wave, &s_total);
    const int rel = qp - t * 32;
    const unsigned ctx = rel <= 0 ? 0u : (rel >= 32 ? 0xFFFFFFFFu : ((1u << rel) - 1u));
    {
        unsigned cands = mwd & ctx;
        while (cands) {
            const int j = __ffs(cands) - 1;
            cands &= cands - 1;
            const int s = segbase + __popc(bwd & ((1u << j) - 1u));
            const unsigned w_ = (unsigned)s >> 5, m_ = 1u << (s & 31);
            if ((segbits[w_] & m_) == 0u) atomicOr(&segbits[w_], m_);
        }
    }
    __syncthreads();
    unsigned m2 = mwd;
    {
        unsigned cand = vwd & ctx & ~mwd;
        while (cand) {
            const int j = __ffs(cand) - 1;
            cand &= cand - 1;
            const int s = segbase + __popc(bwd & ((1u << j) - 1u));
            if ((segbits[(unsigned)s >> 5] >> (s & 31)) & 1u) m2 |= 1u << j;
        }
    }
    int cb = exscan512(__popc(m2), t, s_wave, &s_total);
    int lk = s_total;
    if (lk == 0) {
        int lastv = vwd ? t * 32 + (31 - __clz(vwd)) : -1;
#pragma unroll
        for (int off = 32; off >= 1; off >>= 1) {
            int n = __shfl_down(lastv, off, 64);
            lastv = lastv > n ? lastv : n;
        }
        __syncthreads();
        if ((t & 63) == 0) s_wave[t >> 6] = lastv;
        __syncthreads();
        if (t == 0) {
            int m = -1;
            for (int w = 0; w < 8; ++w) m = m > s_wave[w] ? m : s_wave[w];
            s_fb = m < 0 ? 0 : m;
        }
        __syncthreads();
        const int fb = s_fb, fw = fb >> 5;
        m2 = (t == fw) ? (1u << (fb & 31)) : 0u;
        cb = (t > fw) ? 1 : 0;
        lk = 1;
    }
    mask2w[row * WW + t] = m2;
    wordscan[row * WW + t] = cb;
    if (t == 0) lkarr[row] = lk;
}

__global__ void __launch_bounds__(256) k3_write(
    const int* __restrict__ g_ids, const unsigned* __restrict__ mask2w,
    const int* __restrict__ wordscan, const int* __restrict__ lkarr,
    int* __restrict__ g_out)
{
    const int chunk = blockIdx.x, row = blockIdx.y, t = threadIdx.x;
    const int pos0 = chunk * 2048 + t * 8;
    const int widx = row * WW + (pos0 >> 5);
    const unsigned m2 = mask2w[widx];
    const int base = wordscan[widx];
    const int lk = lkarr[row];
    const int sub = t & 3;
    const unsigned mybits = (m2 >> (8 * sub)) & 0xffu;
    const int off = base + __popc(m2 & ((1u << (8 * sub)) - 1u));
    const int g = row * LL + pos0;
    const int4* idp = (const int4*)(g_ids + g);
    int4 i0 = idp[0], i1 = idp[1];
    const int c = row * LL + off;
    if (mybits == 0xffu && (off & 3) == 0) {
        ((int4*)(g_out + c))[0] = i0;
        ((int4*)(g_out + c))[1] = i1;
    } else if (mybits) {
        int idsv[8] = {i0.x, i0.y, i0.z, i0.w, i1.x, i1.y, i1.z, i1.w};
        int cc = c;
        unsigned mm = mybits;
        while (mm) {
            const int j = __ffs(mm) - 1;
            mm &= mm - 1;
            g_out[cc++] = idsv[j];
        }
    }
    if (pos0 + 7 >= lk) {
#pragma unroll
        for (int j = 0; j < 8; ++j)
            if (pos0 + j >= lk) g_out[g + j] = 0;
    }
    int* attn = g_out + (size_t)BB * LL;
    int* pos  = g_out + (size_t)2 * BB * LL;
    int4 a0, a1, p0, p1;
    a0.x = (pos0 + 0) < lk; a0.y = (pos0 + 1) < lk; a0.z = (pos0 + 2) < lk; a0.w = (pos0 + 3) < lk;
    a1.x = (pos0 + 4) < lk; a1.y = (pos0 + 5) < lk; a1.z = (pos0 + 6) < lk; a1.w = (pos0 + 7) < lk;
    p0.x = a0.x ? pos0 + 0 : 0; p0.y = a0.y ? pos0 + 1 : 0; p0.z = a0.z ? pos0 + 2 : 0; p0.w = a0.w ? pos0 + 3 : 0;
    p1.x = a1.x ? pos0 + 4 : 0; p1.y = a1.y ? pos0 + 5 : 0; p1.z = a1.z ? pos0 + 6 : 0; p1.w = a1.w ? pos0 + 7 : 0;
    ((int4*)(attn + g))[0] = a0;
    ((int4*)(attn + g))[1] = a1;
    ((int4*)(pos + g))[0] = p0;
    ((int4*)(pos + g))[1] = p1;
}

extern "C" void kernel_launch(void* const* d_in, const int* in_sizes, int n_in,
                              void* d_out, int out_size, void* d_ws, size_t ws_size,
                              hipStream_t stream) {
    const int* ids = (const int*)d_in[0];
    const int* am  = (const int*)d_in[1];
    const int* t2p = (const int*)d_in[2];
    const int* kpg = (const int*)d_in[3];
    const int* qp  = (const int*)d_in[4];
    int* out       = (int*)d_out;

    unsigned* segbits = (unsigned*)d_ws;             // BB*SEGW words (128 KB)
    int* aggr_bnd   = (int*)(segbits + BB * SEGW);   // BB*NCH
    int* aggr_kept  = aggr_bnd + BB * NCH;
    int* aggr_lastv = aggr_kept + BB * NCH;

    void* args[] = { (void*)&ids, (void*)&am, (void*)&t2p, (void*)&kpg, (void*)&qp,
                     (void*)&out, (void*)&segbits, (void*)&aggr_bnd,
                     (void*)&aggr_kept, (void*)&aggr_lastv };
    hipError_t e = hipLaunchCooperativeKernel((const void*)coop_seg,
                                              dim3(NCH, BB), dim3(NT),
                                              args, 0, stream);
    if (e != hipSuccess) {
        // fallback: proven 3-kernel pipeline (round-3, passed)
        unsigned* validw = (unsigned*)d_ws;
        unsigned* bndw   = validw + BB * WW;
        unsigned* mask1w = bndw + BB * WW;
        unsigned* mask2w = mask1w + BB * WW;
        int* wordscan    = (int*)(mask2w + BB * WW);
        int* lkarr       = wordscan + BB * WW;
        dim3 gridA(8, BB);
        k1_masks<<<gridA, 256, 0, stream>>>(ids, am, t2p, kpg, qp, validw, bndw, mask1w);
        k2_scan<<<BB, 512, 0, stream>>>(validw, bndw, mask1w, qp, mask2w, wordscan, lkarr);
        k3_write<<<gridA, 256, 0, stream>>>(ids, mask2w, wordscan, lkarr, out);
    }
}

// Round 5
// 95.405 us; speedup vs baseline: 2.5555x; 2.5555x over previous
//
#include <hip/hip_runtime.h>
#include <stdint.h>

#define BB 64
#define LL 16384
#define PP 256
#define NCH 8          // chunks (blocks) per row
#define CHK 2048       // tokens per chunk
#define NT 256         // threads per block
#define TPT 8          // tokens per thread
#define WW (LL / 32)   // 512 bit-words per row

__device__ __forceinline__ int ald(const int* p) {
    return __hip_atomic_load(p, __ATOMIC_RELAXED, __HIP_MEMORY_SCOPE_AGENT);
}
__device__ __forceinline__ void ast(int* p, int v) {
    __hip_atomic_store(p, v, __ATOMIC_RELAXED, __HIP_MEMORY_SCOPE_AGENT);
}
__device__ __forceinline__ unsigned aldu(const unsigned* p) {
    return __hip_atomic_load(p, __ATOMIC_RELAXED, __HIP_MEMORY_SCOPE_AGENT);
}
__device__ __forceinline__ void astu(unsigned* p, unsigned v) {
    __hip_atomic_store(p, v, __ATOMIC_RELAXED, __HIP_MEMORY_SCOPE_AGENT);
}

// exclusive scan over 256 threads (4 waves); *s_tot = block total
__device__ __forceinline__ int exscan256(int v, int tid, int* s_w, int* s_tot) {
    __syncthreads();
    const int lane = tid & 63, wv = tid >> 6;
    int inc = v;
#pragma unroll
    for (int off = 1; off < 64; off <<= 1) {
        int n = __shfl_up(inc, off, 64);
        if (lane >= off) inc += n;
    }
    if (lane == 63) s_w[wv] = inc;
    __syncthreads();
    if (tid == 0) {
        int t = 0;
#pragma unroll
        for (int w = 0; w < 4; ++w) { int u = s_w[w]; s_w[w] = t; t += u; }
        *s_tot = t;
    }
    __syncthreads();
    return inc - v + s_w[wv];
}

__global__ void __launch_bounds__(64) init_state(int* state) {
    state[threadIdx.x] = 0;
}

// state word per row: bits0..3 arrival counter (reaches 8), bit4 done, bits5.. lk
__global__ void __launch_bounds__(NT, 2) fused_seg(
    const int* __restrict__ g_ids, const int* __restrict__ g_amask,
    const int* __restrict__ g_t2p, const int* __restrict__ g_kp,
    const int* __restrict__ g_qp, int* __restrict__ g_out,
    unsigned* __restrict__ validw, unsigned* __restrict__ bndw,
    unsigned* __restrict__ mask1w, unsigned* __restrict__ mask2w,
    int* __restrict__ wordscan, int* __restrict__ state)
{
    __shared__ unsigned char kp[PP];
    __shared__ unsigned s_segw[WW];   // 2 KB segment bitset (master only)
    __shared__ int s_w[4];
    __shared__ int s_tot;
    __shared__ int s_master;
    __shared__ int s_lk;

    const int chunk = blockIdx.x;      // 0..7
    const int row   = blockIdx.y;      // 0..63
    const int tid   = threadIdx.x;     // 0..255
    const int rowoff = row * LL;
    const int pos0 = chunk * CHK + tid * TPT;

    // ---------- Phase A: masks + publish bit-words ----------
    kp[tid] = (g_kp[row * PP + tid] != 0);
    int qp = g_qp[row];
    qp = qp < 0 ? 0 : (qp > LL - 1 ? LL - 1 : qp);
    __syncthreads();

    const int4* idp = (const int4*)(g_ids + rowoff + pos0);
    const int4* amp = (const int4*)(g_amask + rowoff + pos0);
    const int4* tpp = (const int4*)(g_t2p + rowoff + pos0);
    int4 i0 = idp[0], i1 = idp[1];
    unsigned v8 = 0, b8 = 0, m8 = 0;
    {
        int4 a0 = amp[0], a1 = amp[1], q0 = tpp[0], q1 = tpp[1];
        int idsv[8] = {i0.x, i0.y, i0.z, i0.w, i1.x, i1.y, i1.z, i1.w};
        int amv[8]  = {a0.x, a0.y, a0.z, a0.w, a1.x, a1.y, a1.z, a1.w};
        int tpv[8]  = {q0.x, q0.y, q0.z, q0.w, q1.x, q1.y, q1.z, q1.w};
#pragma unroll
        for (int j = 0; j < TPT; ++j) {
            const int va = (amv[j] != 0);
            const int bd = va && (idsv[j] == 13 || idsv[j] == 30);
            int pg = tpv[j];
            pg = pg < 0 ? 0 : (pg > PP - 1 ? PP - 1 : pg);
            const int m1 = va && (kp[pg] || (pos0 + j) >= qp);
            v8 |= (unsigned)va << j;
            b8 |= (unsigned)bd << j;
            m8 |= (unsigned)m1 << j;
        }
    }
    {
        const int sub = tid & 3, sh = 8 * sub;
        unsigned vw = v8 << sh, bw = b8 << sh, mw = m8 << sh;
        vw |= __shfl_xor(vw, 1, 64); vw |= __shfl_xor(vw, 2, 64);
        bw |= __shfl_xor(bw, 1, 64); bw |= __shfl_xor(bw, 2, 64);
        mw |= __shfl_xor(mw, 1, 64); mw |= __shfl_xor(mw, 2, 64);
        if (sub == 0) {
            const int widx = row * WW + chunk * 64 + (tid >> 2);
            astu(&validw[widx], vw); astu(&bndw[widx], bw); astu(&mask1w[widx], mw);
        }
    }
    __syncthreads();   // drains vmcnt(0): atomic stores are device-visible
    if (tid == 0)
        s_master = __hip_atomic_fetch_add(&state[row], 1, __ATOMIC_ACQ_REL,
                                          __HIP_MEMORY_SCOPE_AGENT);
    __syncthreads();
    const bool master = (s_master == 7);   // block-uniform

    int lk;
    if (master) {
        // ---------- Phase B: whole-row scan work (256 thr, 2 words each) ----------
        const int w0i = 2 * tid, w1i = 2 * tid + 1;
        const int base_idx = row * WW;
        const unsigned bw0 = aldu(&bndw[base_idx + w0i]);
        const unsigned bw1 = aldu(&bndw[base_idx + w1i]);
        const unsigned vw0 = aldu(&validw[base_idx + w0i]);
        const unsigned vw1 = aldu(&validw[base_idx + w1i]);
        const unsigned mw0 = aldu(&mask1w[base_idx + w0i]);
        const unsigned mw1 = aldu(&mask1w[base_idx + w1i]);
        s_segw[w0i] = 0u; s_segw[w1i] = 0u;

        const int sb0 = exscan256(__popc(bw0) + __popc(bw1), tid, s_w, &s_tot);
        const int sb1 = sb0 + __popc(bw0);

        const int rel0 = qp - w0i * 32, rel1 = qp - w1i * 32;
        const unsigned ctx0 = rel0 <= 0 ? 0u : (rel0 >= 32 ? 0xFFFFFFFFu : ((1u << rel0) - 1u));
        const unsigned ctx1 = rel1 <= 0 ? 0u : (rel1 >= 32 ? 0xFFFFFFFFu : ((1u << rel1) - 1u));

        // rescue accumulate
#pragma unroll
        for (int h = 0; h < 2; ++h) {
            const unsigned bw_ = h ? bw1 : bw0;
            unsigned cands = h ? (mw1 & ctx1) : (mw0 & ctx0);
            const int sb_ = h ? sb1 : sb0;
            if (bw_ == 0u) {
                if (cands) {
                    const unsigned w_ = (unsigned)sb_ >> 5, m_ = 1u << (sb_ & 31);
                    if ((s_segw[w_] & m_) == 0u) atomicOr(&s_segw[w_], m_);
                }
            } else {
                while (cands) {
                    const int j = __ffs(cands) - 1;
                    cands &= cands - 1;
                    const int s = sb_ + __popc(bw_ & ((1u << j) - 1u));
                    const unsigned w_ = (unsigned)s >> 5, m_ = 1u << (s & 31);
                    if ((s_segw[w_] & m_) == 0u) atomicOr(&s_segw[w_], m_);
                }
            }
        }
        __syncthreads();

        // rescue read
        unsigned m2w0 = mw0, m2w1 = mw1;
#pragma unroll
        for (int h = 0; h < 2; ++h) {
            const unsigned bw_ = h ? bw1 : bw0;
            unsigned cand = h ? (vw1 & ctx1 & ~mw1) : (vw0 & ctx0 & ~mw0);
            const int sb_ = h ? sb1 : sb0;
            unsigned add = 0u;
            if (bw_ == 0u) {
                if (cand && ((s_segw[(unsigned)sb_ >> 5] >> (sb_ & 31)) & 1u)) add = cand;
            } else {
                while (cand) {
                    const int j = __ffs(cand) - 1;
                    cand &= cand - 1;
                    const int s = sb_ + __popc(bw_ & ((1u << j) - 1u));
                    if ((s_segw[(unsigned)s >> 5] >> (s & 31)) & 1u) add |= 1u << j;
                }
            }
            if (h) m2w1 |= add; else m2w0 |= add;
        }

        int cb = exscan256(__popc(m2w0) + __popc(m2w1), tid, s_w, &s_tot);
        lk = s_tot;

        if (lk == 0) {   // fallback: keep last valid token (or position 0)
            int lv = vw1 ? w1i * 32 + (31 - __clz(vw1))
                         : (vw0 ? w0i * 32 + (31 - __clz(vw0)) : -1);
#pragma unroll
            for (int off = 32; off >= 1; off >>= 1) {
                int n = __shfl_down(lv, off, 64);
                lv = lv > n ? lv : n;
            }
            __syncthreads();
            if ((tid & 63) == 0) s_w[tid >> 6] = lv;
            __syncthreads();
            if (tid == 0) {
                int m = -1;
#pragma unroll
                for (int w = 0; w < 4; ++w) m = m > s_w[w] ? m : s_w[w];
                const int fb = m < 0 ? 0 : m;
                g_out[rowoff] = g_ids[rowoff + fb];
            }
            m2w0 = 0u; m2w1 = 0u; cb = 0; lk = 1;
        }

        astu(&mask2w[base_idx + w0i], m2w0);
        astu(&mask2w[base_idx + w1i], m2w1);
        ast(&wordscan[base_idx + w0i], cb);
        ast(&wordscan[base_idx + w1i], cb + __popc(m2w0));
        if (tid == 0) s_lk = lk;
        __syncthreads();   // drains vmcnt(0): results device-visible; s_lk visible
        if (tid == 0)
            __hip_atomic_fetch_add(&state[row], (1 << 4) | (lk << 5),
                                   __ATOMIC_ACQ_REL, __HIP_MEMORY_SCOPE_AGENT);
        lk = s_lk;
    } else {
        if (tid == 0) {
            int s;
            while ((((s = __hip_atomic_load(&state[row], __ATOMIC_RELAXED,
                                            __HIP_MEMORY_SCOPE_AGENT)) >> 4) & 1) == 0)
                __builtin_amdgcn_s_sleep(16);
            s_lk = s >> 5;
        }
        __syncthreads();
        lk = s_lk;
    }

    // ---------- Phase C: scatter + outputs (ids still in registers) ----------
    const int widx = row * WW + chunk * 64 + (tid >> 2);
    const unsigned m2 = aldu(&mask2w[widx]);
    const int wbase = ald(&wordscan[widx]);
    const int sub = tid & 3;
    const unsigned mybits = (m2 >> (8 * sub)) & 0xffu;
    const int off = wbase + __popc(m2 & ((1u << (8 * sub)) - 1u));

    if (mybits == 0xffu && (off & 3) == 0) {
        ((int4*)(g_out + rowoff + off))[0] = i0;
        ((int4*)(g_out + rowoff + off))[1] = i1;
    } else if (mybits) {
        int idsv[8] = {i0.x, i0.y, i0.z, i0.w, i1.x, i1.y, i1.z, i1.w};
        int cc = rowoff + off;
        unsigned mm = mybits;
        while (mm) {
            const int j = __ffs(mm) - 1;
            mm &= mm - 1;
            g_out[cc++] = idsv[j];
        }
    }

    const int g = rowoff + pos0;
    if (pos0 >= lk) {
        int4 z; z.x = z.y = z.z = z.w = 0;
        ((int4*)(g_out + g))[0] = z;
        ((int4*)(g_out + g))[1] = z;
    } else if (pos0 + TPT > lk) {
#pragma unroll
        for (int j = 0; j < TPT; ++j)
            if (pos0 + j >= lk) g_out[g + j] = 0;
    }

    int* attn = g_out + (size_t)BB * LL;
    int* pos  = g_out + (size_t)2 * BB * LL;
    int4 a0, a1, q0, q1;
    a0.x = (pos0 + 0) < lk; a0.y = (pos0 + 1) < lk; a0.z = (pos0 + 2) < lk; a0.w = (pos0 + 3) < lk;
    a1.x = (pos0 + 4) < lk; a1.y = (pos0 + 5) < lk; a1.z = (pos0 + 6) < lk; a1.w = (pos0 + 7) < lk;
    q0.x = a0.x ? pos0 + 0 : 0; q0.y = a0.y ? pos0 + 1 : 0; q0.z = a0.z ? pos0 + 2 : 0; q0.w = a0.w ? pos0 + 3 : 0;
    q1.x = a1.x ? pos0 + 4 : 0; q1.y = a1.y ? pos0 + 5 : 0; q1.z = a1.z ? pos0 + 6 : 0; q1.w = a1.w ? pos0 + 7 : 0;
    ((int4*)(attn + g))[0] = a0;
    ((int4*)(attn + g))[1] = a1;
    ((int4*)(pos + g))[0] = q0;
    ((int4*)(pos + g))[1] = q1;
}

extern "C" void kernel_launch(void* const* d_in, const int* in_sizes, int n_in,
                              void* d_out, int out_size, void* d_ws, size_t ws_size,
                              hipStream_t stream) {
    const int* ids = (const int*)d_in[0];
    const int* am  = (const int*)d_in[1];
    const int* t2p = (const int*)d_in[2];
    const int* kpg = (const int*)d_in[3];
    const int* qp  = (const int*)d_in[4];
    int* out       = (int*)d_out;

    unsigned* validw = (unsigned*)d_ws;           // BB*WW words each
    unsigned* bndw   = validw + BB * WW;
    unsigned* mask1w = bndw + BB * WW;
    unsigned* mask2w = mask1w + BB * WW;
    int* wordscan    = (int*)(mask2w + BB * WW);
    int* state       = wordscan + BB * WW;        // BB ints

    init_state<<<1, 64, 0, stream>>>(state);
    fused_seg<<<dim3(NCH, BB), NT, 0, stream>>>(ids, am, t2p, kpg, qp, out,
                                                validw, bndw, mask1w, mask2w,
                                                wordscan, state);
}

// Round 6
// 83.616 us; speedup vs baseline: 2.9158x; 1.1410x over previous
//
#include <hip/hip_runtime.h>
#include <stdint.h>

#define BB 64
#define LL 16384
#define PP 256
#define WW (LL / 32)   // 512 bit-words per row
#define NT2 512        // K2 threads (one per word)

// ---------------- K1: inputs -> bit arrays (valid/boundary/mask1) ----------------
__global__ void __launch_bounds__(256) k1_masks(
    const int* __restrict__ g_ids, const int* __restrict__ g_amask,
    const int* __restrict__ g_t2p, const int* __restrict__ g_kp,
    const int* __restrict__ g_qp,
    unsigned* __restrict__ validw, unsigned* __restrict__ bndw,
    unsigned* __restrict__ mask1w)
{
    __shared__ unsigned char kp[PP];
    const int chunk = blockIdx.x;    // 0..7  (2048 tokens each)
    const int row   = blockIdx.y;    // 0..63
    const int t     = threadIdx.x;   // 0..255, 8 tokens each
    if (t < PP) kp[t] = (g_kp[row * PP + t] != 0);
    int qp = g_qp[row];
    qp = qp < 0 ? 0 : (qp > LL - 1 ? LL - 1 : qp);
    __syncthreads();

    const int pos0 = chunk * 2048 + t * 8;
    const int g = row * LL + pos0;
    const int4* idp = (const int4*)(g_ids + g);
    const int4* amp = (const int4*)(g_amask + g);
    const int4* tpp = (const int4*)(g_t2p + g);
    unsigned v8 = 0, b8 = 0, m8 = 0;
#pragma unroll
    for (int jv = 0; jv < 2; ++jv) {
        int4 iv = idp[jv], av = amp[jv], pv = tpp[jv];
        int idsv[4] = {iv.x, iv.y, iv.z, iv.w};
        int amv[4]  = {av.x, av.y, av.z, av.w};
        int tpv[4]  = {pv.x, pv.y, pv.z, pv.w};
#pragma unroll
        for (int k = 0; k < 4; ++k) {
            const int j = jv * 4 + k;
            const int va = (amv[k] != 0);
            const int bd = va && (idsv[k] == 13 || idsv[k] == 30);
            int pg = tpv[k];
            pg = pg < 0 ? 0 : (pg > PP - 1 ? PP - 1 : pg);
            const int m1 = va && (kp[pg] || (pos0 + j) >= qp);
            v8 |= (unsigned)va << j;
            b8 |= (unsigned)bd << j;
            m8 |= (unsigned)m1 << j;
        }
    }
    // combine 4 adjacent lanes' bytes into one 32-token word
    const int sub = t & 3, sh = 8 * sub;
    unsigned vw = v8 << sh, bw = b8 << sh, mw = m8 << sh;
    vw |= __shfl_xor(vw, 1, 64); vw |= __shfl_xor(vw, 2, 64);
    bw |= __shfl_xor(bw, 1, 64); bw |= __shfl_xor(bw, 2, 64);
    mw |= __shfl_xor(mw, 1, 64); mw |= __shfl_xor(mw, 2, 64);
    if (sub == 0) {
        const int widx = row * WW + chunk * 64 + (t >> 2);
        validw[widx] = vw; bndw[widx] = bw; mask1w[widx] = mw;
    }
}

// Block exclusive scan over 512 threads (8 waves of 64).
__device__ __forceinline__ int exscan512(int v, int tid, int* s_wave, int* s_total) {
    __syncthreads();
    const int lane = tid & 63, wv = tid >> 6;
    int inc = v;
#pragma unroll
    for (int off = 1; off < 64; off <<= 1) {
        int n = __shfl_up(inc, off, 64);
        if (lane >= off) inc += n;
    }
    if (lane == 63) s_wave[wv] = inc;
    __syncthreads();
    if (wv == 0) {
        int wval = (lane < 8) ? s_wave[lane] : 0;
        int winc = wval;
#pragma unroll
        for (int off = 1; off < 8; off <<= 1) {
            int n = __shfl_up(winc, off, 64);
            if (lane >= off) winc += n;
        }
        if (lane < 8) s_wave[lane] = winc - wval;
        if (lane == 7) *s_total = winc;
    }
    __syncthreads();
    return inc - v + s_wave[wv];
}

// ---------------- K2: scans + sentence rescue + fallback (one block per row) ----------------
__global__ void __launch_bounds__(NT2) k2_scan(
    const unsigned* __restrict__ validw, const unsigned* __restrict__ bndw,
    const unsigned* __restrict__ mask1w, const int* __restrict__ g_qp,
    unsigned* __restrict__ mask2w, int* __restrict__ wordscan,
    int* __restrict__ lkarr)
{
    __shared__ unsigned segbits[WW];   // 2 KB: one bit per possible segment id
    __shared__ int s_wave[8];
    __shared__ int s_total;
    __shared__ int s_fb;
    const int row = blockIdx.x;
    const int t = threadIdx.x;         // word index 0..511
    segbits[t] = 0u;
    int qp = g_qp[row];
    qp = qp < 0 ? 0 : (qp > LL - 1 ? LL - 1 : qp);
    const unsigned vwd = validw[row * WW + t];
    const unsigned bwd = bndw[row * WW + t];
    const unsigned mwd = mask1w[row * WW + t];

    // segment id base for this word = boundaries before it (exscan syncs cover segbits init)
    const int segbase = exscan512(__popc(bwd), t, s_wave, &s_total);

    // in-context bits of this word
    const int rel = qp - t * 32;
    const unsigned ctx = rel <= 0 ? 0u : (rel >= 32 ? 0xFFFFFFFFu : ((1u << rel) - 1u));

    // rescue accumulate: kept in-ctx tokens set their segment's bit
    {
        unsigned cands = mwd & ctx;   // in-ctx => tail false => this is mask0
        if (bwd == 0u) {
            if (cands) {
                const unsigned w_ = (unsigned)segbase >> 5, m_ = 1u << (segbase & 31);
                if ((segbits[w_] & m_) == 0u) atomicOr(&segbits[w_], m_);
            }
        } else {
            while (cands) {
                const int j = __ffs(cands) - 1;
                cands &= cands - 1;
                const int s = segbase + __popc(bwd & ((1u << j) - 1u));
                const unsigned w_ = (unsigned)s >> 5, m_ = 1u << (s & 31);
                if ((segbits[w_] & m_) == 0u) atomicOr(&segbits[w_], m_);
            }
        }
    }
    __syncthreads();

    // rescue read: in-ctx valid not-yet-kept tokens join if their segment bit is set
    unsigned m2 = mwd;
    {
        unsigned cand = vwd & ctx & ~mwd;
        if (bwd == 0u) {
            if (cand && ((segbits[(unsigned)segbase >> 5] >> (segbase & 31)) & 1u)) m2 |= cand;
        } else {
            while (cand) {
                const int j = __ffs(cand) - 1;
                cand &= cand - 1;
                const int s = segbase + __popc(bwd & ((1u << j) - 1u));
                if ((segbits[(unsigned)s >> 5] >> (s & 31)) & 1u) m2 |= 1u << j;
            }
        }
    }

    // compaction scan
    int cb = exscan512(__popc(m2), t, s_wave, &s_total);
    int lk = s_total;

    // fallback: nothing kept -> keep last valid token (or position 0)
    if (lk == 0) {
        int lastv = vwd ? t * 32 + (31 - __clz(vwd)) : -1;
#pragma unroll
        for (int off = 32; off >= 1; off >>= 1) {
            int n = __shfl_down(lastv, off, 64);
            lastv = lastv > n ? lastv : n;
        }
        __syncthreads();
        if ((t & 63) == 0) s_wave[t >> 6] = lastv;
        __syncthreads();
        if (t == 0) {
            int m = -1;
            for (int w = 0; w < 8; ++w) m = m > s_wave[w] ? m : s_wave[w];
            s_fb = m < 0 ? 0 : m;
        }
        __syncthreads();
        const int fb = s_fb, fw = fb >> 5;
        m2 = (t == fw) ? (1u << (fb & 31)) : 0u;
        cb = (t > fw) ? 1 : 0;
        lk = 1;
    }

    mask2w[row * WW + t] = m2;
    wordscan[row * WW + t] = cb;
    if (t == 0) lkarr[row] = lk;
}

// ---------------- K3: scatter-compact ids + attn/pos/pad ----------------
__global__ void __launch_bounds__(256) k3_write(
    const int* __restrict__ g_ids, const unsigned* __restrict__ mask2w,
    const int* __restrict__ wordscan, const int* __restrict__ lkarr,
    int* __restrict__ g_out)
{
    const int chunk = blockIdx.x;    // 0..7
    const int row   = blockIdx.y;    // 0..63
    const int t     = threadIdx.x;   // 0..255, 8 tokens each
    const int pos0 = chunk * 2048 + t * 8;
    const int widx = row * WW + (pos0 >> 5);
    const unsigned m2 = mask2w[widx];
    const int base = wordscan[widx];
    const int lk = lkarr[row];
    const int sub = t & 3;
    const unsigned mybits = (m2 >> (8 * sub)) & 0xffu;
    const int off = base + __popc(m2 & ((1u << (8 * sub)) - 1u));

    const int g = row * LL + pos0;
    const int4* idp = (const int4*)(g_ids + g);
    int4 i0 = idp[0], i1 = idp[1];

    // scatter kept ids (stable, monotone destinations)
    const int c = row * LL + off;
    if (mybits == 0xffu && (off & 3) == 0) {
        ((int4*)(g_out + c))[0] = i0;
        ((int4*)(g_out + c))[1] = i1;
    } else if (mybits) {
        int idsv[8] = {i0.x, i0.y, i0.z, i0.w, i1.x, i1.y, i1.z, i1.w};
        int cc = c;
        unsigned mm = mybits;
        while (mm) {
            const int j = __ffs(mm) - 1;
            mm &= mm - 1;
            g_out[cc++] = idsv[j];
        }
    }

    // pad ids tail
    if (pos0 + 7 >= lk) {
#pragma unroll
        for (int j = 0; j < 8; ++j)
            if (pos0 + j >= lk) g_out[g + j] = 0;
    }

    // attn / pos
    int* attn = g_out + (size_t)BB * LL;
    int* pos  = g_out + (size_t)2 * BB * LL;
    int4 a0, a1, p0, p1;
    a0.x = (pos0 + 0) < lk; a0.y = (pos0 + 1) < lk; a0.z = (pos0 + 2) < lk; a0.w = (pos0 + 3) < lk;
    a1.x = (pos0 + 4) < lk; a1.y = (pos0 + 5) < lk; a1.z = (pos0 + 6) < lk; a1.w = (pos0 + 7) < lk;
    p0.x = a0.x ? pos0 + 0 : 0; p0.y = a0.y ? pos0 + 1 : 0; p0.z = a0.z ? pos0 + 2 : 0; p0.w = a0.w ? pos0 + 3 : 0;
    p1.x = a1.x ? pos0 + 4 : 0; p1.y = a1.y ? pos0 + 5 : 0; p1.z = a1.z ? pos0 + 6 : 0; p1.w = a1.w ? pos0 + 7 : 0;
    ((int4*)(attn + g))[0] = a0;
    ((int4*)(attn + g))[1] = a1;
    ((int4*)(pos + g))[0] = p0;
    ((int4*)(pos + g))[1] = p1;
}

extern "C" void kernel_launch(void* const* d_in, const int* in_sizes, int n_in,
                              void* d_out, int out_size, void* d_ws, size_t ws_size,
                              hipStream_t stream) {
    const int* ids = (const int*)d_in[0];
    const int* am  = (const int*)d_in[1];
    const int* t2p = (const int*)d_in[2];
    const int* kpg = (const int*)d_in[3];
    const int* qp  = (const int*)d_in[4];
    int* out       = (int*)d_out;

    unsigned* validw = (unsigned*)d_ws;
    unsigned* bndw   = validw + BB * WW;
    unsigned* mask1w = bndw + BB * WW;
    unsigned* mask2w = mask1w + BB * WW;
    int* wordscan    = (int*)(mask2w + BB * WW);
    int* lkarr       = wordscan + BB * WW;

    dim3 gridA(8, BB);
    k1_masks<<<gridA, 256, 0, stream>>>(ids, am, t2p, kpg, qp, validw, bndw, mask1w);
    k2_scan<<<BB, NT2, 0, stream>>>(validw, bndw, mask1w, qp, mask2w, wordscan, lkarr);
    k3_write<<<gridA, 256, 0, stream>>>(ids, mask2w, wordscan, lkarr, out);
}